// Round 10
// baseline (710.950 us; speedup 1.0000x reference)
//
#include <hip/hip_runtime.h>

#define D 128
#define H 256
#define NBLK 512          // partition blocks
#define BUCKSH 8          // bucket = dst >> 8  (256 nodes/bucket)

typedef _Float16 half8 __attribute__((ext_vector_type(8)));
typedef _Float16 half4 __attribute__((ext_vector_type(4)));
typedef float floatx4 __attribute__((ext_vector_type(4)));
typedef float floatx2 __attribute__((ext_vector_type(2)));

__device__ inline unsigned char f32_to_fp8(float v){
  int p = __builtin_amdgcn_cvt_pk_fp8_f32(v, v, 0, false);
  return (unsigned char)(p & 0xFF);
}

// ======== multi-block exclusive scan ========
__global__ __launch_bounds__(256) void scan_part(const int* __restrict__ cnt,
                                                 int* __restrict__ bsum, int N){
  int base = blockIdx.x*1024;
  int tid = threadIdx.x;
  int idx = base + tid*4;
  int4 v = {0,0,0,0};
  if (idx + 3 < N) v = *(const int4*)(cnt + idx);
  else {
    if (idx   < N) v.x = cnt[idx];
    if (idx+1 < N) v.y = cnt[idx+1];
    if (idx+2 < N) v.z = cnt[idx+2];
    if (idx+3 < N) v.w = cnt[idx+3];
  }
  int s = v.x + v.y + v.z + v.w;
  #pragma unroll
  for (int off = 32; off > 0; off >>= 1) s += __shfl_down(s, off, 64);
  __shared__ int ws[4];
  int lane = tid & 63, wave = tid >> 6;
  if (lane == 0) ws[wave] = s;
  __syncthreads();
  if (tid == 0) bsum[blockIdx.x] = ws[0] + ws[1] + ws[2] + ws[3];
}

__global__ __launch_bounds__(1024) void scan_bsums(const int* __restrict__ bsum,
                                                   int* __restrict__ bbase,
                                                   int* __restrict__ total_out, int nb, int N){
  __shared__ int sh[1024];
  int tid = threadIdx.x;
  int v = (tid < nb) ? bsum[tid] : 0;
  sh[tid] = v;
  __syncthreads();
  #pragma unroll
  for (int off = 1; off < 1024; off <<= 1){
    int t = 0;
    if (tid >= off) t = sh[tid - off];
    __syncthreads();
    if (tid >= off) sh[tid] += t;
    __syncthreads();
  }
  if (tid < nb) bbase[tid] = sh[tid] - v;
  if (tid == 0) total_out[N] = sh[1023];   // grand total at [N]
}

__global__ __launch_bounds__(256) void scan_emit(const int* __restrict__ cnt,
                                                 const int* __restrict__ bbase,
                                                 int* __restrict__ outp, int N){
  int base = blockIdx.x*1024;
  int tid = threadIdx.x;
  int idx = base + tid*4;
  int4 v = {0,0,0,0};
  if (idx + 3 < N) v = *(const int4*)(cnt + idx);
  else {
    if (idx   < N) v.x = cnt[idx];
    if (idx+1 < N) v.y = cnt[idx+1];
    if (idx+2 < N) v.z = cnt[idx+2];
    if (idx+3 < N) v.w = cnt[idx+3];
  }
  int s = v.x + v.y + v.z + v.w;
  int lane = tid & 63, wave = tid >> 6;
  int incl = s;
  #pragma unroll
  for (int off = 1; off < 64; off <<= 1){
    int t = __shfl_up(incl, off, 64);
    if (lane >= off) incl += t;
  }
  __shared__ int ws[4];
  if (lane == 63) ws[wave] = incl;
  __syncthreads();
  int woff = 0;
  #pragma unroll
  for (int w = 0; w < 4; ++w) if (w < wave) woff += ws[w];
  int off0 = bbase[blockIdx.x] + woff + (incl - s);
  if (idx   < N) outp[idx]   = off0;
  if (idx+1 < N) outp[idx+1] = off0 + v.x;
  if (idx+2 < N) outp[idx+2] = off0 + v.x + v.y;
  if (idx+3 < N) outp[idx+3] = off0 + v.x + v.y + v.z;
}

// ======== 3-pass CSR partition build (staged entry packed in ONE uint) ========
// staged = (dloc<<24) | (code<<20) | src ; packed = staged & 0xFFFFFF
__global__ __launch_bounds__(256) void part_count(const int* __restrict__ dst,
                                                  int* __restrict__ cntBB,
                                                  int E, int chunk, int nbuck){
  __shared__ int lc[512];
  int b = blockIdx.x;
  for (int i = threadIdx.x; i < nbuck; i += 256) lc[i] = 0;
  __syncthreads();
  int e0 = b*chunk, e1 = min(e0 + chunk, E);
  for (int e = e0 + threadIdx.x; e < e1; e += 256)
    atomicAdd(&lc[dst[e] >> BUCKSH], 1);
  __syncthreads();
  for (int i = threadIdx.x; i < nbuck; i += 256) cntBB[i*NBLK + b] = lc[i];
}

__global__ __launch_bounds__(256) void part_bin(const int* __restrict__ src,
                                                const int* __restrict__ dst,
                                                const int* __restrict__ ea,
                                                const int* __restrict__ baseBB,
                                                unsigned* __restrict__ staged,
                                                int E, int chunk, int nbuck){
  __shared__ int run[512];
  int b = blockIdx.x;
  for (int i = threadIdx.x; i < nbuck; i += 256) run[i] = baseBB[i*NBLK + b];
  __syncthreads();
  int e0 = b*chunk, e1 = min(e0 + chunk, E);
  for (int e = e0 + threadIdx.x; e < e1; e += 256){
    int d = dst[e];
    unsigned pv = ((unsigned)(d & 255) << 24) |
                  ((unsigned)(ea[2*e]*3 + ea[2*e+1]) << 20) | (unsigned)src[e];
    int pos = atomicAdd(&run[d >> BUCKSH], 1);
    staged[pos] = pv;
  }
}

__global__ __launch_bounds__(256) void part_emit(const unsigned* __restrict__ staged,
                                                 const int* __restrict__ baseBB,
                                                 unsigned* __restrict__ packed,
                                                 int* __restrict__ rowptr,
                                                 int N, int E, int nbuck, int M){
  __shared__ int ncnt[256];
  __shared__ int sscan[256];
  __shared__ int basep[256];
  __shared__ int cur[256];
  int k = blockIdx.x;
  int tid = threadIdx.x;
  int bstart = baseBB[k*NBLK];
  int bend = (k+1 < nbuck) ? baseBB[(k+1)*NBLK] : baseBB[M];
  ncnt[tid] = 0; cur[tid] = 0;
  __syncthreads();
  for (int j = bstart + tid; j < bend; j += 256)
    atomicAdd(&ncnt[staged[j] >> 24], 1);
  __syncthreads();
  int v = ncnt[tid];
  sscan[tid] = v;
  __syncthreads();
  #pragma unroll
  for (int off = 1; off < 256; off <<= 1){
    int t = (tid >= off) ? sscan[tid-off] : 0;
    __syncthreads();
    sscan[tid] += t;
    __syncthreads();
  }
  int excl = sscan[tid] - v;
  basep[tid] = bstart + excl;
  int node = k*256 + tid;
  if (node < N) rowptr[node] = bstart + excl;
  if (k == nbuck-1 && tid == 0) rowptr[N] = E;
  __syncthreads();
  for (int j = bstart + tid; j < bend; j += 256){
    unsigned s = staged[j];
    int dloc = (int)(s >> 24);
    int pos = basep[dloc] + atomicAdd(&cur[dloc], 1);
    packed[pos] = s & 0xFFFFFFu;
  }
}

// ---------------- input embedding (fp8 h table) ----------------
__global__ void embed_kernel(const int* __restrict__ x, const float* __restrict__ xemb,
                             unsigned char* __restrict__ h, int N){
  int t = blockIdx.x*256 + threadIdx.x;
  if (t >= N*16) return;
  int n = t >> 4, c = (t & 15) * 8;
  int x0 = x[2*n], x1 = x[2*n+1];
  const float* r0 = xemb + (size_t)x0*D + c;
  const float* r1 = xemb + (size_t)(120 + x1)*D + c;
  float f[8];
  #pragma unroll
  for (int j = 0; j < 8; ++j) f[j] = r0[j] + r1[j];
  int w0 = 0, w1v = 0;
  w0  = __builtin_amdgcn_cvt_pk_fp8_f32(f[0], f[1], w0,  false);
  w0  = __builtin_amdgcn_cvt_pk_fp8_f32(f[2], f[3], w0,  true);
  w1v = __builtin_amdgcn_cvt_pk_fp8_f32(f[4], f[5], w1v, false);
  w1v = __builtin_amdgcn_cvt_pk_fp8_f32(f[6], f[7], w1v, true);
  uint2 o; o.x = (unsigned)w0; o.y = (unsigned)w1v;
  *(uint2*)(h + (size_t)n*D + c) = o;     // row stride D bytes (fp8)
}

// ---------------- per-layer constant tables ----------------
__global__ void prep_tables(const float* __restrict__ etab, const float* __restrict__ gamma,
                            const float* __restrict__ beta, const float* __restrict__ mean,
                            const float* __restrict__ var, const float* __restrict__ b2,
                            float* __restrict__ comb, float* __restrict__ sc, float* __restrict__ sh){
  int l = blockIdx.x, d = threadIdx.x;
  const float* et = etab + (size_t)l*9*D;
  float* cl = comb + (size_t)l*10*D;
  #pragma unroll
  for (int b = 0; b < 3; ++b)
    #pragma unroll
    for (int dd = 0; dd < 3; ++dd)
      cl[(b*3+dd)*D + d] = et[b*D + d] + et[(6+dd)*D + d];
  cl[9*D + d] = et[4*D + d] + et[6*D + d];
  float A = gamma[l*D+d] * rsqrtf(var[l*D+d] + 1e-5f);
  sc[l*D+d] = A;
  sh[l*D+d] = (b2[l*D+d] - mean[l*D+d]) * A + beta[l*D+d];
}

// repack weights fragment-major for coalesced B loads
__global__ void repack_weights(const float* __restrict__ w1, const float* __restrict__ w2,
                               _Float16* __restrict__ w1f, _Float16* __restrict__ w2f, int total){
  int i = blockIdx.x*256 + threadIdx.x;
  if (i >= total) return;                 // total = 5*H*D
  int l = i / (H*D), r = i % (H*D);
  {
    int n = r / D, k = r % D;
    w1f[(size_t)l*H*D + (size_t)(k>>3)*(H*8) + n*8 + (k&7)] = (_Float16)w1[i];
  }
  {
    int n2 = r / H, k2 = r % H;
    w2f[(size_t)l*D*H + (size_t)(k2>>3)*(D*8) + n2*8 + (k2&7)] = (_Float16)w2[i];
  }
}

// ---------------- FUSED layer: R6-shape gather (4 nodes/wave x 4 iters) -> atile -> MLP
// Each 4-wave block owns 64 nodes. Gather phase = 4 iterations of the verified
// round-6 agg body (4 nodes/wave, 16 fp8 dwordx2 gathers in flight, p/pn index
// prefetch — DO NOT restructure, r7 lesson). Result written directly into the
// swizzled atile. Then GEMM1+ReLU -> hmid -> GEMM2+BN identical to mlp_kernel.
// LDS: 32KB atile/hmid (aliased) + 5KB comb = 37KB -> 4 blocks/CU.
__global__ __launch_bounds__(256) void gin_fused(
    const unsigned char* __restrict__ hin, const unsigned* __restrict__ packed,
    const int* __restrict__ rowptr, const float* __restrict__ comb,
    const _Float16* __restrict__ w1f, const _Float16* __restrict__ w2f,
    const float* __restrict__ b1, const float* __restrict__ sc,
    const float* __restrict__ sh, unsigned char* __restrict__ hout,
    float* __restrict__ fout, int N, int relu_out){
  __shared__ __align__(16) char smem[64*256*2 + 10*128*4];
  _Float16* atile = (_Float16*)smem;   // row*128 + (c8 ^ (row&15))*8 + (col&7)
  _Float16* hmid  = (_Float16*)smem;   // row*256 + (c8 ^ (row&31))*8 + (col&7)
  float* cl = (float*)(smem + 64*256*2);
  int tid = threadIdx.x;
  int wave = tid >> 6, lane = tid & 63;
  int quad = lane >> 4, l15 = lane & 15;
  int r0 = blockIdx.x * 64;

  for (int i = tid; i < 10*D; i += 256) cl[i] = comb[i];
  __syncthreads();

  // ---- gather phase (R6 body x 4 iterations per wave) ----
  int q = lane >> 4, l16 = lane & 15;
  int c = l16 * 8;                        // 8 fp8 dims per lane
  #pragma unroll 1
  for (int it = 0; it < 4; ++it){
    int row = wave*16 + it*4 + q;
    int node = r0 + row;
    bool valid = node < N;
    int nd = valid ? node : 0;
    float a0, a1, a2, a3, a4, a5, a6, a7;
    {
      uint2 hx = *(const uint2*)(hin + (size_t)nd*D + c);
      floatx2 s0 = __builtin_amdgcn_cvt_pk_f32_fp8((int)hx.x, false);
      floatx2 s1 = __builtin_amdgcn_cvt_pk_f32_fp8((int)hx.x, true);
      floatx2 s2 = __builtin_amdgcn_cvt_pk_f32_fp8((int)hx.y, false);
      floatx2 s3 = __builtin_amdgcn_cvt_pk_f32_fp8((int)hx.y, true);
      a0 = s0[0] + cl[9*D + c    ];
      a1 = s0[1] + cl[9*D + c + 1];
      a2 = s1[0] + cl[9*D + c + 2];
      a3 = s1[1] + cl[9*D + c + 3];
      a4 = s2[0] + cl[9*D + c + 4];
      a5 = s2[1] + cl[9*D + c + 5];
      a6 = s3[0] + cl[9*D + c + 6];
      a7 = s3[1] + cl[9*D + c + 7];
    }
    int beg = rowptr[nd], end = rowptr[nd+1];
    unsigned long long cp = 0;             // 9 codes x 7-bit counters
    unsigned p[16], pn[16];
    {
      int m0 = end - beg;
      #pragma unroll
      for (int k = 0; k < 16; ++k) if (k < m0) p[k] = packed[beg+k];
    }
    for (int j = beg; j < end; j += 16){
      int m = end - j;                     // uniform within quarter
      uint2 v[16];
      #pragma unroll
      for (int k = 0; k < 16; ++k) if (k < m)
        v[k] = *(const uint2*)(hin + (size_t)(p[k] & 0xFFFFFu)*D + c);
      int mn = end - (j + 16);             // prefetch next batch's indices
      #pragma unroll
      for (int k = 0; k < 16; ++k) if (k < mn) pn[k] = packed[j+16+k];
      #pragma unroll
      for (int k = 0; k < 16; ++k) if (k < m){
        cp += 1ULL << (7*(int)(p[k] >> 20));
        floatx2 g0 = __builtin_amdgcn_cvt_pk_f32_fp8((int)v[k].x, false);
        floatx2 g1 = __builtin_amdgcn_cvt_pk_f32_fp8((int)v[k].x, true);
        floatx2 g2 = __builtin_amdgcn_cvt_pk_f32_fp8((int)v[k].y, false);
        floatx2 g3 = __builtin_amdgcn_cvt_pk_f32_fp8((int)v[k].y, true);
        a0 += g0[0]; a1 += g0[1]; a2 += g1[0]; a3 += g1[1];
        a4 += g2[0]; a5 += g2[1]; a6 += g3[0]; a7 += g3[1];
      }
      #pragma unroll
      for (int k = 0; k < 16; ++k) p[k] = pn[k];
    }
    #pragma unroll
    for (int cd = 0; cd < 9; ++cd){
      float cnt = (float)(int)((cp >> (7*cd)) & 127);
      a0 += cnt * cl[cd*D + c    ];
      a1 += cnt * cl[cd*D + c + 1];
      a2 += cnt * cl[cd*D + c + 2];
      a3 += cnt * cl[cd*D + c + 3];
      a4 += cnt * cl[cd*D + c + 4];
      a5 += cnt * cl[cd*D + c + 5];
      a6 += cnt * cl[cd*D + c + 6];
      a7 += cnt * cl[cd*D + c + 7];
    }
    half8 o;
    o[0] = (_Float16)a0; o[1] = (_Float16)a1;
    o[2] = (_Float16)a2; o[3] = (_Float16)a3;
    o[4] = (_Float16)a4; o[5] = (_Float16)a5;
    o[6] = (_Float16)a6; o[7] = (_Float16)a7;
    // garbage rows (node>=N) are finite and masked at the epilogue (row-local in MFMA)
    *(half8*)(atile + row*128 + ((l16 ^ (row & 15)) * 8)) = o;
  }
  __syncthreads();

  // ---- GEMM1 (A=atile 64x128, B=w1f 128x256) + ReLU -> hmid ----
  floatx4 acc[4][4] = {};
  half8 bcur[4], bnxt[4];
  #pragma unroll
  for (int nt = 0; nt < 4; ++nt)
    bcur[nt] = *(const half8*)(w1f + (size_t)quad*(H*8) + (wave*64 + nt*16 + l15)*8);
  #pragma unroll
  for (int ks = 0; ks < 4; ++ks){
    if (ks < 3){
      #pragma unroll
      for (int nt = 0; nt < 4; ++nt)
        bnxt[nt] = *(const half8*)(w1f + (size_t)((ks+1)*4 + quad)*(H*8) + (wave*64 + nt*16 + l15)*8);
    }
    int c8 = ks*4 + quad;
    half8 af[4];
    #pragma unroll
    for (int mt = 0; mt < 4; ++mt)
      af[mt] = *(const half8*)(atile + (mt*16 + l15)*128 + ((c8 ^ l15) * 8));
    #pragma unroll
    for (int mt = 0; mt < 4; ++mt)
      #pragma unroll
      for (int nt = 0; nt < 4; ++nt)
        acc[mt][nt] = __builtin_amdgcn_mfma_f32_16x16x32_f16(af[mt], bcur[nt], acc[mt][nt], 0, 0, 0);
    #pragma unroll
    for (int nt = 0; nt < 4; ++nt) bcur[nt] = bnxt[nt];
  }
  __syncthreads();

  #pragma unroll
  for (int nt = 0; nt < 4; ++nt){
    int n = wave*64 + nt*16 + l15;
    float bias = b1[n];
    #pragma unroll
    for (int mt = 0; mt < 4; ++mt)
      #pragma unroll
      for (int r = 0; r < 4; ++r){
        int row = mt*16 + quad*4 + r;
        hmid[row*256 + (((n >> 3) ^ (row & 31)) * 8) + (n & 7)] =
            (_Float16)fmaxf(acc[mt][nt][r] + bias, 0.f);
      }
  }
  __syncthreads();

  // ---- GEMM2 (A=hmid 64x256, B=w2f 256x128) + BN ----
  floatx4 acc2[4][2] = {};
  half8 gcur[2], gnxt[2];
  #pragma unroll
  for (int nt = 0; nt < 2; ++nt)
    gcur[nt] = *(const half8*)(w2f + (size_t)quad*(D*8) + (wave*32 + nt*16 + l15)*8);
  #pragma unroll
  for (int ks = 0; ks < 8; ++ks){
    if (ks < 7){
      #pragma unroll
      for (int nt = 0; nt < 2; ++nt)
        gnxt[nt] = *(const half8*)(w2f + (size_t)((ks+1)*4 + quad)*(D*8) + (wave*32 + nt*16 + l15)*8);
    }
    int c8 = ks*4 + quad;
    half8 af[4];
    #pragma unroll
    for (int mt = 0; mt < 4; ++mt){
      int row = mt*16 + l15;
      af[mt] = *(const half8*)(hmid + row*256 + ((c8 ^ (row & 31)) * 8));
    }
    #pragma unroll
    for (int mt = 0; mt < 4; ++mt)
      #pragma unroll
      for (int nt = 0; nt < 2; ++nt)
        acc2[mt][nt] = __builtin_amdgcn_mfma_f32_16x16x32_f16(af[mt], gcur[nt], acc2[mt][nt], 0, 0, 0);
    #pragma unroll
    for (int nt = 0; nt < 2; ++nt) gcur[nt] = gnxt[nt];
  }

  #pragma unroll
  for (int nt = 0; nt < 2; ++nt){
    int n = wave*32 + nt*16 + l15;
    float A = sc[n], B = sh[n];
    #pragma unroll
    for (int mt = 0; mt < 4; ++mt)
      #pragma unroll
      for (int r = 0; r < 4; ++r){
        int row = r0 + mt*16 + quad*4 + r;
        if (row < N){
          float v = acc2[mt][nt][r]*A + B;
          if (relu_out) v = fmaxf(v, 0.f);
          if (fout) fout[(size_t)row*D + n] = v;
          else      hout[(size_t)row*D + n] = f32_to_fp8(v);
        }
      }
  }
}

extern "C" void kernel_launch(void* const* d_in, const int* in_sizes, int n_in,
                              void* d_out, int out_size, void* d_ws, size_t ws_size,
                              hipStream_t stream){
  const int*   x     = (const int*)d_in[0];
  const int*   ei    = (const int*)d_in[1];
  const int*   ea    = (const int*)d_in[2];
  const float* xemb  = (const float*)d_in[3];
  const float* etab  = (const float*)d_in[4];
  const float* w1    = (const float*)d_in[5];
  const float* b1    = (const float*)d_in[6];
  const float* w2    = (const float*)d_in[7];
  const float* b2    = (const float*)d_in[8];
  const float* gamma = (const float*)d_in[9];
  const float* beta  = (const float*)d_in[10];
  const float* mean  = (const float*)d_in[11];
  const float* var   = (const float*)d_in[12];
  float* out = (float*)d_out;

  int N = in_sizes[0] / 2;
  int E = in_sizes[1] / 2;
  int nbuck = (N + 255) >> 8;
  int M = nbuck * NBLK;
  int nbM = (M + 1023) / 1024;
  int chunk = (E + NBLK - 1) / NBLK;

  char* ws = (char*)d_ws;
  size_t off = 0;
  auto alloc = [&](size_t b){ void* p = ws + off; off += (b + 255) & ~(size_t)255; return p; };
  unsigned char* ha  = (unsigned char*)alloc((size_t)N*D);      // fp8 node table ping
  unsigned char* hb  = (unsigned char*)alloc((size_t)N*D);      // fp8 node table pong (staged aliases)
  unsigned* packed   = (unsigned*)alloc((size_t)(E+64)*4);
  int*      rowptr   = (int*)alloc((size_t)(N+1)*4);
  int*      cntBB    = (int*)alloc((size_t)M*4);
  int*      baseBB   = (int*)alloc((size_t)(M+1)*4);
  int*      bsum     = (int*)alloc((size_t)nbM*4);
  int*      bbase    = (int*)alloc((size_t)nbM*4);
  _Float16* w1f      = (_Float16*)alloc((size_t)5*H*D*2);
  _Float16* w2f      = (_Float16*)alloc((size_t)5*D*H*2);
  float*    comb     = (float*)alloc((size_t)5*10*D*4);
  float*    sc       = (float*)alloc((size_t)5*D*4);
  float*    sh       = (float*)alloc((size_t)5*D*4);
  unsigned* staged   = (unsigned*)hb;   // dead before layer 0 writes hb (E*4 <= N*D)

  const int* srcp = ei;
  const int* dstp = ei + E;

  part_count<<<NBLK, 256, 0, stream>>>(dstp, cntBB, E, chunk, nbuck);
  scan_part <<<nbM, 256, 0, stream>>>(cntBB, bsum, M);
  scan_bsums<<<1, 1024, 0, stream>>>(bsum, bbase, baseBB, nbM, M);   // baseBB[M] = E
  scan_emit <<<nbM, 256, 0, stream>>>(cntBB, bbase, baseBB, M);
  part_bin  <<<NBLK, 256, 0, stream>>>(srcp, dstp, ea, baseBB, staged, E, chunk, nbuck);
  part_emit <<<nbuck, 256, 0, stream>>>(staged, baseBB, packed, rowptr, N, E, nbuck, M);
  repack_weights<<<(5*H*D+255)/256, 256, 0, stream>>>(w1, w2, w1f, w2f, 5*H*D);
  prep_tables<<<5, 128, 0, stream>>>(etab, gamma, beta, mean, var, b2, comb, sc, sh);
  embed_kernel<<<((size_t)N*16+255)/256, 256, 0, stream>>>(x, xemb, ha, N);

  const unsigned char* hin = ha;
  unsigned char* hob = hb;
  for (int l = 0; l < 5; ++l){
    int last = (l == 4);
    gin_fused<<<(N+63)/64, 256, 0, stream>>>(hin, packed, rowptr,
        comb + (size_t)l*10*D, w1f + (size_t)l*H*D, w2f + (size_t)l*D*H,
        b1 + (size_t)l*H, sc + (size_t)l*D, sh + (size_t)l*D,
        last ? (unsigned char*)nullptr : hob, last ? out : (float*)nullptr,
        N, last ? 0 : 1);
    unsigned char* t = (unsigned char*)hin; hin = hob; hob = t;
  }
}

// Round 12
// 642.662 us; speedup vs baseline: 1.1063x; 1.1063x over previous
//
#include <hip/hip_runtime.h>

#define D 128
#define H 256
#define NBLK 512          // partition blocks
#define BUCKSH 8          // bucket = dst >> 8  (256 nodes/bucket)

typedef _Float16 half8 __attribute__((ext_vector_type(8)));
typedef _Float16 half4 __attribute__((ext_vector_type(4)));
typedef float floatx4 __attribute__((ext_vector_type(4)));
typedef float floatx2 __attribute__((ext_vector_type(2)));

__device__ inline unsigned char f32_to_fp8(float v){
  int p = __builtin_amdgcn_cvt_pk_fp8_f32(v, v, 0, false);
  return (unsigned char)(p & 0xFF);
}

// ======== multi-block exclusive scan ========
__global__ __launch_bounds__(256) void scan_part(const int* __restrict__ cnt,
                                                 int* __restrict__ bsum, int N){
  int base = blockIdx.x*1024;
  int tid = threadIdx.x;
  int idx = base + tid*4;
  int4 v = {0,0,0,0};
  if (idx + 3 < N) v = *(const int4*)(cnt + idx);
  else {
    if (idx   < N) v.x = cnt[idx];
    if (idx+1 < N) v.y = cnt[idx+1];
    if (idx+2 < N) v.z = cnt[idx+2];
    if (idx+3 < N) v.w = cnt[idx+3];
  }
  int s = v.x + v.y + v.z + v.w;
  #pragma unroll
  for (int off = 32; off > 0; off >>= 1) s += __shfl_down(s, off, 64);
  __shared__ int ws[4];
  int lane = tid & 63, wave = tid >> 6;
  if (lane == 0) ws[wave] = s;
  __syncthreads();
  if (tid == 0) bsum[blockIdx.x] = ws[0] + ws[1] + ws[2] + ws[3];
}

__global__ __launch_bounds__(1024) void scan_bsums(const int* __restrict__ bsum,
                                                   int* __restrict__ bbase,
                                                   int* __restrict__ total_out, int nb, int N){
  __shared__ int sh[1024];
  int tid = threadIdx.x;
  int v = (tid < nb) ? bsum[tid] : 0;
  sh[tid] = v;
  __syncthreads();
  #pragma unroll
  for (int off = 1; off < 1024; off <<= 1){
    int t = 0;
    if (tid >= off) t = sh[tid - off];
    __syncthreads();
    if (tid >= off) sh[tid] += t;
    __syncthreads();
  }
  if (tid < nb) bbase[tid] = sh[tid] - v;
  if (tid == 0) total_out[N] = sh[1023];   // grand total at [N]
}

__global__ __launch_bounds__(256) void scan_emit(const int* __restrict__ cnt,
                                                 const int* __restrict__ bbase,
                                                 int* __restrict__ outp, int N){
  int base = blockIdx.x*1024;
  int tid = threadIdx.x;
  int idx = base + tid*4;
  int4 v = {0,0,0,0};
  if (idx + 3 < N) v = *(const int4*)(cnt + idx);
  else {
    if (idx   < N) v.x = cnt[idx];
    if (idx+1 < N) v.y = cnt[idx+1];
    if (idx+2 < N) v.z = cnt[idx+2];
    if (idx+3 < N) v.w = cnt[idx+3];
  }
  int s = v.x + v.y + v.z + v.w;
  int lane = tid & 63, wave = tid >> 6;
  int incl = s;
  #pragma unroll
  for (int off = 1; off < 64; off <<= 1){
    int t = __shfl_up(incl, off, 64);
    if (lane >= off) incl += t;
  }
  __shared__ int ws[4];
  if (lane == 63) ws[wave] = incl;
  __syncthreads();
  int woff = 0;
  #pragma unroll
  for (int w = 0; w < 4; ++w) if (w < wave) woff += ws[w];
  int off0 = bbase[blockIdx.x] + woff + (incl - s);
  if (idx   < N) outp[idx]   = off0;
  if (idx+1 < N) outp[idx+1] = off0 + v.x;
  if (idx+2 < N) outp[idx+2] = off0 + v.x + v.y;
  if (idx+3 < N) outp[idx+3] = off0 + v.x + v.y + v.z;
}

// ======== 3-pass CSR partition build (staged entry packed in ONE uint) ========
// staged = (dloc<<24) | (code<<20) | src ; packed = staged & 0xFFFFFF
__global__ __launch_bounds__(256) void part_count(const int* __restrict__ dst,
                                                  int* __restrict__ cntBB,
                                                  int E, int chunk, int nbuck){
  __shared__ int lc[512];
  int b = blockIdx.x;
  for (int i = threadIdx.x; i < nbuck; i += 256) lc[i] = 0;
  __syncthreads();
  int e0 = b*chunk, e1 = min(e0 + chunk, E);
  for (int e = e0 + threadIdx.x; e < e1; e += 256)
    atomicAdd(&lc[dst[e] >> BUCKSH], 1);
  __syncthreads();
  for (int i = threadIdx.x; i < nbuck; i += 256) cntBB[i*NBLK + b] = lc[i];
}

__global__ __launch_bounds__(256) void part_bin(const int* __restrict__ src,
                                                const int* __restrict__ dst,
                                                const int* __restrict__ ea,
                                                const int* __restrict__ baseBB,
                                                unsigned* __restrict__ staged,
                                                int E, int chunk, int nbuck){
  __shared__ int run[512];
  int b = blockIdx.x;
  for (int i = threadIdx.x; i < nbuck; i += 256) run[i] = baseBB[i*NBLK + b];
  __syncthreads();
  int e0 = b*chunk, e1 = min(e0 + chunk, E);
  for (int e = e0 + threadIdx.x; e < e1; e += 256){
    int d = dst[e];
    unsigned pv = ((unsigned)(d & 255) << 24) |
                  ((unsigned)(ea[2*e]*3 + ea[2*e+1]) << 20) | (unsigned)src[e];
    int pos = atomicAdd(&run[d >> BUCKSH], 1);
    staged[pos] = pv;
  }
}

__global__ __launch_bounds__(256) void part_emit(const unsigned* __restrict__ staged,
                                                 const int* __restrict__ baseBB,
                                                 unsigned* __restrict__ packed,
                                                 int* __restrict__ rowptr,
                                                 int N, int E, int nbuck, int M){
  __shared__ int ncnt[256];
  __shared__ int sscan[256];
  __shared__ int basep[256];
  __shared__ int cur[256];
  int k = blockIdx.x;
  int tid = threadIdx.x;
  int bstart = baseBB[k*NBLK];
  int bend = (k+1 < nbuck) ? baseBB[(k+1)*NBLK] : baseBB[M];
  ncnt[tid] = 0; cur[tid] = 0;
  __syncthreads();
  for (int j = bstart + tid; j < bend; j += 256)
    atomicAdd(&ncnt[staged[j] >> 24], 1);
  __syncthreads();
  int v = ncnt[tid];
  sscan[tid] = v;
  __syncthreads();
  #pragma unroll
  for (int off = 1; off < 256; off <<= 1){
    int t = (tid >= off) ? sscan[tid-off] : 0;
    __syncthreads();
    sscan[tid] += t;
    __syncthreads();
  }
  int excl = sscan[tid] - v;
  basep[tid] = bstart + excl;
  int node = k*256 + tid;
  if (node < N) rowptr[node] = bstart + excl;
  if (k == nbuck-1 && tid == 0) rowptr[N] = E;
  __syncthreads();
  for (int j = bstart + tid; j < bend; j += 256){
    unsigned s = staged[j];
    int dloc = (int)(s >> 24);
    int pos = basep[dloc] + atomicAdd(&cur[dloc], 1);
    packed[pos] = s & 0xFFFFFFu;
  }
}

// ---------------- input embedding (fp8 h table) ----------------
__global__ void embed_kernel(const int* __restrict__ x, const float* __restrict__ xemb,
                             unsigned char* __restrict__ h, int N){
  int t = blockIdx.x*256 + threadIdx.x;
  if (t >= N*16) return;
  int n = t >> 4, c = (t & 15) * 8;
  int x0 = x[2*n], x1 = x[2*n+1];
  const float* r0 = xemb + (size_t)x0*D + c;
  const float* r1 = xemb + (size_t)(120 + x1)*D + c;
  float f[8];
  #pragma unroll
  for (int j = 0; j < 8; ++j) f[j] = r0[j] + r1[j];
  int w0 = 0, w1v = 0;
  w0  = __builtin_amdgcn_cvt_pk_fp8_f32(f[0], f[1], w0,  false);
  w0  = __builtin_amdgcn_cvt_pk_fp8_f32(f[2], f[3], w0,  true);
  w1v = __builtin_amdgcn_cvt_pk_fp8_f32(f[4], f[5], w1v, false);
  w1v = __builtin_amdgcn_cvt_pk_fp8_f32(f[6], f[7], w1v, true);
  uint2 o; o.x = (unsigned)w0; o.y = (unsigned)w1v;
  *(uint2*)(h + (size_t)n*D + c) = o;     // row stride D bytes (fp8)
}

// ---------------- per-layer constant tables ----------------
__global__ void prep_tables(const float* __restrict__ etab, const float* __restrict__ gamma,
                            const float* __restrict__ beta, const float* __restrict__ mean,
                            const float* __restrict__ var, const float* __restrict__ b2,
                            float* __restrict__ comb, float* __restrict__ sc, float* __restrict__ sh){
  int l = blockIdx.x, d = threadIdx.x;
  const float* et = etab + (size_t)l*9*D;
  float* cl = comb + (size_t)l*10*D;
  #pragma unroll
  for (int b = 0; b < 3; ++b)
    #pragma unroll
    for (int dd = 0; dd < 3; ++dd)
      cl[(b*3+dd)*D + d] = et[b*D + d] + et[(6+dd)*D + d];
  cl[9*D + d] = et[4*D + d] + et[6*D + d];
  float A = gamma[l*D+d] * rsqrtf(var[l*D+d] + 1e-5f);
  sc[l*D+d] = A;
  sh[l*D+d] = (b2[l*D+d] - mean[l*D+d]) * A + beta[l*D+d];
}

// repack weights fragment-major for coalesced B loads
__global__ void repack_weights(const float* __restrict__ w1, const float* __restrict__ w2,
                               _Float16* __restrict__ w1f, _Float16* __restrict__ w2f, int total){
  int i = blockIdx.x*256 + threadIdx.x;
  if (i >= total) return;                 // total = 5*H*D
  int l = i / (H*D), r = i % (H*D);
  {
    int n = r / D, k = r % D;
    w1f[(size_t)l*H*D + (size_t)(k>>3)*(H*8) + n*8 + (k&7)] = (_Float16)w1[i];
  }
  {
    int n2 = r / H, k2 = r % H;
    w2f[(size_t)l*D*H + (size_t)(k2>>3)*(D*8) + n2*8 + (k2&7)] = (_Float16)w2[i];
  }
}

// ---------------- aggregation: FOUR nodes per wave (16 lanes each), fp8 gathers ----------------
// R6 exact shape (verified 50.3 us): single v[16] gather buffer, p/pn index prefetch,
// in-loop cp code counting. DO NOT restructure (r7: manual pipelining -2.3x;
// r8: cpt hoist null). Fusion with MLP is dead (r2/r10: concurrency loss > glue saved).
__global__ __launch_bounds__(256) void agg_kernel(
    const unsigned char* __restrict__ h, const unsigned* __restrict__ packed,
    const int* __restrict__ rowptr, const float* __restrict__ comb,
    _Float16* __restrict__ agg, int N){
  __shared__ float cl[10*D];
  int tid = threadIdx.x;
  for (int i = tid; i < 10*D; i += 256) cl[i] = comb[i];
  __syncthreads();
  int lane = tid & 63;
  int q = lane >> 4, l16 = lane & 15;     // quarter index, lane-in-quarter
  int node = blockIdx.x*16 + (tid >> 6)*4 + q;
  bool valid = node < N;
  int nd = valid ? node : 0;
  int c = l16 * 8;                        // 8 fp8 dims per lane
  float a0, a1, a2, a3, a4, a5, a6, a7;
  {
    uint2 hx = *(const uint2*)(h + (size_t)nd*D + c);
    floatx2 s0 = __builtin_amdgcn_cvt_pk_f32_fp8((int)hx.x, false);
    floatx2 s1 = __builtin_amdgcn_cvt_pk_f32_fp8((int)hx.x, true);
    floatx2 s2 = __builtin_amdgcn_cvt_pk_f32_fp8((int)hx.y, false);
    floatx2 s3 = __builtin_amdgcn_cvt_pk_f32_fp8((int)hx.y, true);
    a0 = s0[0] + cl[9*D + c    ];
    a1 = s0[1] + cl[9*D + c + 1];
    a2 = s1[0] + cl[9*D + c + 2];
    a3 = s1[1] + cl[9*D + c + 3];
    a4 = s2[0] + cl[9*D + c + 4];
    a5 = s2[1] + cl[9*D + c + 5];
    a6 = s3[0] + cl[9*D + c + 6];
    a7 = s3[1] + cl[9*D + c + 7];
  }
  int beg = rowptr[nd], end = rowptr[nd+1];
  unsigned long long cp = 0;             // 9 codes x 7-bit counters
  unsigned p[16], pn[16];
  {
    int m0 = end - beg;
    #pragma unroll
    for (int k = 0; k < 16; ++k) if (k < m0) p[k] = packed[beg+k];
  }
  for (int j = beg; j < end; j += 16){
    int m = end - j;                     // uniform within quarter
    uint2 v[16];
    #pragma unroll
    for (int k = 0; k < 16; ++k) if (k < m)
      v[k] = *(const uint2*)(h + (size_t)(p[k] & 0xFFFFFu)*D + c);
    int mn = end - (j + 16);             // prefetch next batch's indices
    #pragma unroll
    for (int k = 0; k < 16; ++k) if (k < mn) pn[k] = packed[j+16+k];
    #pragma unroll
    for (int k = 0; k < 16; ++k) if (k < m){
      cp += 1ULL << (7*(int)(p[k] >> 20));
      floatx2 g0 = __builtin_amdgcn_cvt_pk_f32_fp8((int)v[k].x, false);
      floatx2 g1 = __builtin_amdgcn_cvt_pk_f32_fp8((int)v[k].x, true);
      floatx2 g2 = __builtin_amdgcn_cvt_pk_f32_fp8((int)v[k].y, false);
      floatx2 g3 = __builtin_amdgcn_cvt_pk_f32_fp8((int)v[k].y, true);
      a0 += g0[0]; a1 += g0[1]; a2 += g1[0]; a3 += g1[1];
      a4 += g2[0]; a5 += g2[1]; a6 += g3[0]; a7 += g3[1];
    }
    #pragma unroll
    for (int k = 0; k < 16; ++k) p[k] = pn[k];
  }
  #pragma unroll
  for (int cd = 0; cd < 9; ++cd){
    float cnt = (float)(int)((cp >> (7*cd)) & 127);
    a0 += cnt * cl[cd*D + c    ];
    a1 += cnt * cl[cd*D + c + 1];
    a2 += cnt * cl[cd*D + c + 2];
    a3 += cnt * cl[cd*D + c + 3];
    a4 += cnt * cl[cd*D + c + 4];
    a5 += cnt * cl[cd*D + c + 5];
    a6 += cnt * cl[cd*D + c + 6];
    a7 += cnt * cl[cd*D + c + 7];
  }
  if (valid){
    half8 o;
    o[0] = (_Float16)a0; o[1] = (_Float16)a1;
    o[2] = (_Float16)a2; o[3] = (_Float16)a3;
    o[4] = (_Float16)a4; o[5] = (_Float16)a5;
    o[6] = (_Float16)a6; o[7] = (_Float16)a7;
    *(half8*)(agg + (size_t)node*D + c) = o;
  }
}

// ---------------- GIN MLP: GEMM1 with DIRECT global A loads -> hmid LDS -> GEMM2+BN
// A-fragment for 16x16x32 at K-step ks is agg[row=l15][ks*32+quad*8 ..+7] — a direct
// 16B half8 load (L2-hot, each fragment read once, no reuse) so LDS staging + 2 of 3
// barriers are pure overhead. hmid stays in LDS (layout transform GEMM1->GEMM2).
// Rows >= N clamp to N-1 (finite, masked at epilogue).
__global__ __launch_bounds__(256) void mlp_kernel(
    const _Float16* __restrict__ agg, const _Float16* __restrict__ w1f,
    const _Float16* __restrict__ w2f, const float* __restrict__ b1,
    const float* __restrict__ sc, const float* __restrict__ sh,
    unsigned char* __restrict__ hout, float* __restrict__ fout,
    int N, int relu_out){
  __shared__ __align__(16) char smem[64*256*2];
  _Float16* hmid = (_Float16*)smem;    // row*256 + (c8 ^ (row&31))*8 + (col&7)
  int tid = threadIdx.x;
  int wave = tid >> 6, lane = tid & 63;
  int quad = lane >> 4, l15 = lane & 15;
  int r0 = blockIdx.x * 64;

  // ---- GEMM1 (A direct from agg, B=w1f 128x256) + ReLU -> hmid ----
  int arow = r0 + l15;                   // rows arow, arow+16, arow+32, arow+48
  floatx4 acc[4][4] = {};
  half8 bcur[4], bnxt[4];
  #pragma unroll
  for (int nt = 0; nt < 4; ++nt)
    bcur[nt] = *(const half8*)(w1f + (size_t)quad*(H*8) + (wave*64 + nt*16 + l15)*8);
  #pragma unroll
  for (int ks = 0; ks < 4; ++ks){
    if (ks < 3){
      #pragma unroll
      for (int nt = 0; nt < 4; ++nt)
        bnxt[nt] = *(const half8*)(w1f + (size_t)((ks+1)*4 + quad)*(H*8) + (wave*64 + nt*16 + l15)*8);
    }
    int kc = ks*32 + quad*8;
    half8 af[4];
    #pragma unroll
    for (int mt = 0; mt < 4; ++mt){
      int row = min(arow + mt*16, N-1);
      af[mt] = *(const half8*)(agg + (size_t)row*D + kc);
    }
    #pragma unroll
    for (int mt = 0; mt < 4; ++mt)
      #pragma unroll
      for (int nt = 0; nt < 4; ++nt)
        acc[mt][nt] = __builtin_amdgcn_mfma_f32_16x16x32_f16(af[mt], bcur[nt], acc[mt][nt], 0, 0, 0);
    #pragma unroll
    for (int nt = 0; nt < 4; ++nt) bcur[nt] = bnxt[nt];
  }

  #pragma unroll
  for (int nt = 0; nt < 4; ++nt){
    int n = wave*64 + nt*16 + l15;
    float bias = b1[n];
    #pragma unroll
    for (int mt = 0; mt < 4; ++mt)
      #pragma unroll
      for (int r = 0; r < 4; ++r){
        int row = mt*16 + quad*4 + r;
        hmid[row*256 + (((n >> 3) ^ (row & 31)) * 8) + (n & 7)] =
            (_Float16)fmaxf(acc[mt][nt][r] + bias, 0.f);
      }
  }
  __syncthreads();

  // ---- GEMM2 (A=hmid 64x256, B=w2f 256x128) + BN ----
  floatx4 acc2[4][2] = {};
  half8 gcur[2], gnxt[2];
  #pragma unroll
  for (int nt = 0; nt < 2; ++nt)
    gcur[nt] = *(const half8*)(w2f + (size_t)quad*(D*8) + (wave*32 + nt*16 + l15)*8);
  #pragma unroll
  for (int ks = 0; ks < 8; ++ks){
    if (ks < 7){
      #pragma unroll
      for (int nt = 0; nt < 2; ++nt)
        gnxt[nt] = *(const half8*)(w2f + (size_t)((ks+1)*4 + quad)*(D*8) + (wave*32 + nt*16 + l15)*8);
    }
    int c8 = ks*4 + quad;
    half8 af[4];
    #pragma unroll
    for (int mt = 0; mt < 4; ++mt){
      int row = mt*16 + l15;
      af[mt] = *(const half8*)(hmid + row*256 + ((c8 ^ (row & 31)) * 8));
    }
    #pragma unroll
    for (int mt = 0; mt < 4; ++mt)
      #pragma unroll
      for (int nt = 0; nt < 2; ++nt)
        acc2[mt][nt] = __builtin_amdgcn_mfma_f32_16x16x32_f16(af[mt], gcur[nt], acc2[mt][nt], 0, 0, 0);
    #pragma unroll
    for (int nt = 0; nt < 2; ++nt) gcur[nt] = gnxt[nt];
  }

  #pragma unroll
  for (int nt = 0; nt < 2; ++nt){
    int n = wave*32 + nt*16 + l15;
    float A = sc[n], B = sh[n];
    #pragma unroll
    for (int mt = 0; mt < 4; ++mt)
      #pragma unroll
      for (int r = 0; r < 4; ++r){
        int row = r0 + mt*16 + quad*4 + r;
        if (row < N){
          float v = acc2[mt][nt][r]*A + B;
          if (relu_out) v = fmaxf(v, 0.f);
          if (fout) fout[(size_t)row*D + n] = v;
          else      hout[(size_t)row*D + n] = f32_to_fp8(v);
        }
      }
  }
}

extern "C" void kernel_launch(void* const* d_in, const int* in_sizes, int n_in,
                              void* d_out, int out_size, void* d_ws, size_t ws_size,
                              hipStream_t stream){
  const int*   x     = (const int*)d_in[0];
  const int*   ei    = (const int*)d_in[1];
  const int*   ea    = (const int*)d_in[2];
  const float* xemb  = (const float*)d_in[3];
  const float* etab  = (const float*)d_in[4];
  const float* w1    = (const float*)d_in[5];
  const float* b1    = (const float*)d_in[6];
  const float* w2    = (const float*)d_in[7];
  const float* b2    = (const float*)d_in[8];
  const float* gamma = (const float*)d_in[9];
  const float* beta  = (const float*)d_in[10];
  const float* mean  = (const float*)d_in[11];
  const float* var   = (const float*)d_in[12];
  float* out = (float*)d_out;

  int N = in_sizes[0] / 2;
  int E = in_sizes[1] / 2;
  int nbuck = (N + 255) >> 8;
  int M = nbuck * NBLK;
  int nbM = (M + 1023) / 1024;
  int chunk = (E + NBLK - 1) / NBLK;

  char* ws = (char*)d_ws;
  size_t off = 0;
  auto alloc = [&](size_t b){ void* p = ws + off; off += (b + 255) & ~(size_t)255; return p; };
  unsigned char* h   = (unsigned char*)alloc((size_t)N*D);      // fp8 node table
  _Float16* agg      = (_Float16*)alloc((size_t)N*D*2);         // staged aliases this
  unsigned* packed   = (unsigned*)alloc((size_t)(E+64)*4);
  int*      rowptr   = (int*)alloc((size_t)(N+1)*4);
  int*      cntBB    = (int*)alloc((size_t)M*4);
  int*      baseBB   = (int*)alloc((size_t)(M+1)*4);
  int*      bsum     = (int*)alloc((size_t)nbM*4);
  int*      bbase    = (int*)alloc((size_t)nbM*4);
  _Float16* w1f      = (_Float16*)alloc((size_t)5*H*D*2);
  _Float16* w2f      = (_Float16*)alloc((size_t)5*D*H*2);
  float*    comb     = (float*)alloc((size_t)5*10*D*4);
  float*    sc       = (float*)alloc((size_t)5*D*4);
  float*    sh       = (float*)alloc((size_t)5*D*4);
  unsigned* staged   = (unsigned*)agg;   // dead before agg_kernel first writes agg

  const int* srcp = ei;
  const int* dstp = ei + E;

  part_count<<<NBLK, 256, 0, stream>>>(dstp, cntBB, E, chunk, nbuck);
  scan_part <<<nbM, 256, 0, stream>>>(cntBB, bsum, M);
  scan_bsums<<<1, 1024, 0, stream>>>(bsum, bbase, baseBB, nbM, M);   // baseBB[M] = E
  scan_emit <<<nbM, 256, 0, stream>>>(cntBB, bbase, baseBB, M);
  part_bin  <<<NBLK, 256, 0, stream>>>(srcp, dstp, ea, baseBB, staged, E, chunk, nbuck);
  part_emit <<<nbuck, 256, 0, stream>>>(staged, baseBB, packed, rowptr, N, E, nbuck, M);
  repack_weights<<<(5*H*D+255)/256, 256, 0, stream>>>(w1, w2, w1f, w2f, 5*H*D);
  prep_tables<<<5, 128, 0, stream>>>(etab, gamma, beta, mean, var, b2, comb, sc, sh);
  embed_kernel<<<((size_t)N*16+255)/256, 256, 0, stream>>>(x, xemb, h, N);

  for (int l = 0; l < 5; ++l){
    agg_kernel<<<(N+15)/16, 256, 0, stream>>>(h, packed, rowptr, comb + (size_t)l*10*D, agg, N);
    int last = (l == 4);
    mlp_kernel<<<(N+63)/64, 256, 0, stream>>>(agg, w1f + (size_t)l*H*D, w2f + (size_t)l*D*H,
        b1 + (size_t)l*H, sc + (size_t)l*D, sh + (size_t)l*D,
        last ? (unsigned char*)nullptr : h, last ? out : (float*)nullptr,
        N, last ? 0 : 1);
  }
}

// Round 14
// 546.331 us; speedup vs baseline: 1.3013x; 1.1763x over previous
//
#include <hip/hip_runtime.h>

#define D 128
#define H 256
#define NBLK 512          // partition blocks
#define BUCKSH 8          // bucket = dst >> 8  (256 nodes/bucket)

typedef _Float16 half8 __attribute__((ext_vector_type(8)));
typedef float floatx4 __attribute__((ext_vector_type(4)));
typedef float floatx2 __attribute__((ext_vector_type(2)));

__device__ inline unsigned char f32_to_fp8(float v){
  int p = __builtin_amdgcn_cvt_pk_fp8_f32(v, v, 0, false);
  return (unsigned char)(p & 0xFF);
}

// ======== multi-block exclusive scan ========
__global__ __launch_bounds__(256) void scan_part(const int* __restrict__ cnt,
                                                 int* __restrict__ bsum, int N){
  int base = blockIdx.x*1024;
  int tid = threadIdx.x;
  int idx = base + tid*4;
  int4 v = {0,0,0,0};
  if (idx + 3 < N) v = *(const int4*)(cnt + idx);
  else {
    if (idx   < N) v.x = cnt[idx];
    if (idx+1 < N) v.y = cnt[idx+1];
    if (idx+2 < N) v.z = cnt[idx+2];
    if (idx+3 < N) v.w = cnt[idx+3];
  }
  int s = v.x + v.y + v.z + v.w;
  #pragma unroll
  for (int off = 32; off > 0; off >>= 1) s += __shfl_down(s, off, 64);
  __shared__ int ws[4];
  int lane = tid & 63, wave = tid >> 6;
  if (lane == 0) ws[wave] = s;
  __syncthreads();
  if (tid == 0) bsum[blockIdx.x] = ws[0] + ws[1] + ws[2] + ws[3];
}

__global__ __launch_bounds__(1024) void scan_bsums(const int* __restrict__ bsum,
                                                   int* __restrict__ bbase,
                                                   int* __restrict__ total_out, int nb, int N){
  __shared__ int sh[1024];
  int tid = threadIdx.x;
  int v = (tid < nb) ? bsum[tid] : 0;
  sh[tid] = v;
  __syncthreads();
  #pragma unroll
  for (int off = 1; off < 1024; off <<= 1){
    int t = 0;
    if (tid >= off) t = sh[tid - off];
    __syncthreads();
    if (tid >= off) sh[tid] += t;
    __syncthreads();
  }
  if (tid < nb) bbase[tid] = sh[tid] - v;
  if (tid == 0) total_out[N] = sh[1023];   // grand total at [N]
}

__global__ __launch_bounds__(256) void scan_emit(const int* __restrict__ cnt,
                                                 const int* __restrict__ bbase,
                                                 int* __restrict__ outp, int N){
  int base = blockIdx.x*1024;
  int tid = threadIdx.x;
  int idx = base + tid*4;
  int4 v = {0,0,0,0};
  if (idx + 3 < N) v = *(const int4*)(cnt + idx);
  else {
    if (idx   < N) v.x = cnt[idx];
    if (idx+1 < N) v.y = cnt[idx+1];
    if (idx+2 < N) v.z = cnt[idx+2];
    if (idx+3 < N) v.w = cnt[idx+3];
  }
  int s = v.x + v.y + v.z + v.w;
  int lane = tid & 63, wave = tid >> 6;
  int incl = s;
  #pragma unroll
  for (int off = 1; off < 64; off <<= 1){
    int t = __shfl_up(incl, off, 64);
    if (lane >= off) incl += t;
  }
  __shared__ int ws[4];
  if (lane == 63) ws[wave] = incl;
  __syncthreads();
  int woff = 0;
  #pragma unroll
  for (int w = 0; w < 4; ++w) if (w < wave) woff += ws[w];
  int off0 = bbase[blockIdx.x] + woff + (incl - s);
  if (idx   < N) outp[idx]   = off0;
  if (idx+1 < N) outp[idx+1] = off0 + v.x;
  if (idx+2 < N) outp[idx+2] = off0 + v.x + v.y;
  if (idx+3 < N) outp[idx+3] = off0 + v.x + v.y + v.z;
}

// ======== 3-pass CSR partition build (staged entry packed in ONE uint) ========
// staged = (dloc<<24) | (code<<20) | src ; packed = staged & 0xFFFFFF
__global__ __launch_bounds__(256) void part_count(const int* __restrict__ dst,
                                                  int* __restrict__ cntBB,
                                                  int E, int chunk, int nbuck){
  __shared__ int lc[512];
  int b = blockIdx.x;
  for (int i = threadIdx.x; i < nbuck; i += 256) lc[i] = 0;
  __syncthreads();
  int e0 = b*chunk, e1 = min(e0 + chunk, E);
  for (int e = e0 + threadIdx.x; e < e1; e += 256)
    atomicAdd(&lc[dst[e] >> BUCKSH], 1);
  __syncthreads();
  for (int i = threadIdx.x; i < nbuck; i += 256) cntBB[i*NBLK + b] = lc[i];
}

__global__ __launch_bounds__(256) void part_bin(const int* __restrict__ src,
                                                const int* __restrict__ dst,
                                                const int* __restrict__ ea,
                                                const int* __restrict__ baseBB,
                                                unsigned* __restrict__ staged,
                                                int E, int chunk, int nbuck){
  __shared__ int run[512];
  int b = blockIdx.x;
  for (int i = threadIdx.x; i < nbuck; i += 256) run[i] = baseBB[i*NBLK + b];
  __syncthreads();
  int e0 = b*chunk, e1 = min(e0 + chunk, E);
  for (int e = e0 + threadIdx.x; e < e1; e += 256){
    int d = dst[e];
    unsigned pv = ((unsigned)(d & 255) << 24) |
                  ((unsigned)(ea[2*e]*3 + ea[2*e+1]) << 20) | (unsigned)src[e];
    int pos = atomicAdd(&run[d >> BUCKSH], 1);
    staged[pos] = pv;
  }
}

__global__ __launch_bounds__(256) void part_emit(const unsigned* __restrict__ staged,
                                                 const int* __restrict__ baseBB,
                                                 unsigned* __restrict__ packed,
                                                 int* __restrict__ rowptr,
                                                 int N, int E, int nbuck, int M){
  __shared__ int ncnt[256];
  __shared__ int sscan[256];
  __shared__ int basep[256];
  __shared__ int cur[256];
  int k = blockIdx.x;
  int tid = threadIdx.x;
  int bstart = baseBB[k*NBLK];
  int bend = (k+1 < nbuck) ? baseBB[(k+1)*NBLK] : baseBB[M];
  ncnt[tid] = 0; cur[tid] = 0;
  __syncthreads();
  for (int j = bstart + tid; j < bend; j += 256)
    atomicAdd(&ncnt[staged[j] >> 24], 1);
  __syncthreads();
  int v = ncnt[tid];
  sscan[tid] = v;
  __syncthreads();
  #pragma unroll
  for (int off = 1; off < 256; off <<= 1){
    int t = (tid >= off) ? sscan[tid-off] : 0;
    __syncthreads();
    sscan[tid] += t;
    __syncthreads();
  }
  int excl = sscan[tid] - v;
  basep[tid] = bstart + excl;
  int node = k*256 + tid;
  if (node < N) rowptr[node] = bstart + excl;
  if (k == nbuck-1 && tid == 0) rowptr[N] = E;
  __syncthreads();
  for (int j = bstart + tid; j < bend; j += 256){
    unsigned s = staged[j];
    int dloc = (int)(s >> 24);
    int pos = basep[dloc] + atomicAdd(&cur[dloc], 1);
    packed[pos] = s & 0xFFFFFFu;
  }
}

// ---------------- input embedding (fp8 h table) ----------------
__global__ void embed_kernel(const int* __restrict__ x, const float* __restrict__ xemb,
                             unsigned char* __restrict__ h, int N){
  int t = blockIdx.x*256 + threadIdx.x;
  if (t >= N*16) return;
  int n = t >> 4, c = (t & 15) * 8;
  int x0 = x[2*n], x1 = x[2*n+1];
  const float* r0 = xemb + (size_t)x0*D + c;
  const float* r1 = xemb + (size_t)(120 + x1)*D + c;
  float f[8];
  #pragma unroll
  for (int j = 0; j < 8; ++j) f[j] = r0[j] + r1[j];
  int w0 = 0, w1v = 0;
  w0  = __builtin_amdgcn_cvt_pk_fp8_f32(f[0], f[1], w0,  false);
  w0  = __builtin_amdgcn_cvt_pk_fp8_f32(f[2], f[3], w0,  true);
  w1v = __builtin_amdgcn_cvt_pk_fp8_f32(f[4], f[5], w1v, false);
  w1v = __builtin_amdgcn_cvt_pk_fp8_f32(f[6], f[7], w1v, true);
  uint2 o; o.x = (unsigned)w0; o.y = (unsigned)w1v;
  *(uint2*)(h + (size_t)n*D + c) = o;     // row stride D bytes (fp8)
}

// ---------------- per-layer constant tables ----------------
__global__ void prep_tables(const float* __restrict__ etab, const float* __restrict__ gamma,
                            const float* __restrict__ beta, const float* __restrict__ mean,
                            const float* __restrict__ var, const float* __restrict__ b2,
                            float* __restrict__ comb, float* __restrict__ sc, float* __restrict__ sh){
  int l = blockIdx.x, d = threadIdx.x;
  const float* et = etab + (size_t)l*9*D;
  float* cl = comb + (size_t)l*10*D;
  #pragma unroll
  for (int b = 0; b < 3; ++b)
    #pragma unroll
    for (int dd = 0; dd < 3; ++dd)
      cl[(b*3+dd)*D + d] = et[b*D + d] + et[(6+dd)*D + d];
  cl[9*D + d] = et[4*D + d] + et[6*D + d];
  float A = gamma[l*D+d] * rsqrtf(var[l*D+d] + 1e-5f);
  sc[l*D+d] = A;
  sh[l*D+d] = (b2[l*D+d] - mean[l*D+d]) * A + beta[l*D+d];
}

// repack weights fragment-major for coalesced B loads
__global__ void repack_weights(const float* __restrict__ w1, const float* __restrict__ w2,
                               _Float16* __restrict__ w1f, _Float16* __restrict__ w2f, int total){
  int i = blockIdx.x*256 + threadIdx.x;
  if (i >= total) return;                 // total = 5*H*D
  int l = i / (H*D), r = i % (H*D);
  {
    int n = r / D, k = r % D;
    w1f[(size_t)l*H*D + (size_t)(k>>3)*(H*8) + n*8 + (k&7)] = (_Float16)w1[i];
  }
  {
    int n2 = r / H, k2 = r % H;
    w2f[(size_t)l*D*H + (size_t)(k2>>3)*(D*8) + n2*8 + (k2&7)] = (_Float16)w2[i];
  }
}

// ---------------- aggregation: EIGHT nodes per wave (8 lanes each), fp8 gathers ----------------
// R6 loop shape (verified: 2->4 nodes/wave tracked iteration count, 76.6->50.4us).
// One dwordx4/lane x 8 lanes covers a full 128B fp8 row; one wave-gather serves 8 edges.
// Single v[16] buffer + p/pn index prefetch — DO NOT restructure (r7 lesson).
__global__ __launch_bounds__(256) void agg_kernel(
    const unsigned char* __restrict__ h, const unsigned* __restrict__ packed,
    const int* __restrict__ rowptr, const float* __restrict__ comb,
    _Float16* __restrict__ agg, int N){
  __shared__ float cl[10*D];
  int tid = threadIdx.x;
  for (int i = tid; i < 10*D; i += 256) cl[i] = comb[i];
  __syncthreads();
  int lane = tid & 63;
  int g = lane >> 3, l8 = lane & 7;       // 8-lane group, lane-in-group
  int node = blockIdx.x*32 + (tid >> 6)*8 + g;
  bool valid = node < N;
  int nd = valid ? node : 0;
  int c = l8 * 16;                        // 16 fp8 dims per lane
  float a[16];
  {
    uint4 hx = *(const uint4*)(h + (size_t)nd*D + c);
    floatx2 s0 = __builtin_amdgcn_cvt_pk_f32_fp8((int)hx.x, false);
    floatx2 s1 = __builtin_amdgcn_cvt_pk_f32_fp8((int)hx.x, true);
    floatx2 s2 = __builtin_amdgcn_cvt_pk_f32_fp8((int)hx.y, false);
    floatx2 s3 = __builtin_amdgcn_cvt_pk_f32_fp8((int)hx.y, true);
    floatx2 s4 = __builtin_amdgcn_cvt_pk_f32_fp8((int)hx.z, false);
    floatx2 s5 = __builtin_amdgcn_cvt_pk_f32_fp8((int)hx.z, true);
    floatx2 s6 = __builtin_amdgcn_cvt_pk_f32_fp8((int)hx.w, false);
    floatx2 s7 = __builtin_amdgcn_cvt_pk_f32_fp8((int)hx.w, true);
    a[0]=s0[0]+cl[9*D+c+0];  a[1]=s0[1]+cl[9*D+c+1];
    a[2]=s1[0]+cl[9*D+c+2];  a[3]=s1[1]+cl[9*D+c+3];
    a[4]=s2[0]+cl[9*D+c+4];  a[5]=s2[1]+cl[9*D+c+5];
    a[6]=s3[0]+cl[9*D+c+6];  a[7]=s3[1]+cl[9*D+c+7];
    a[8]=s4[0]+cl[9*D+c+8];  a[9]=s4[1]+cl[9*D+c+9];
    a[10]=s5[0]+cl[9*D+c+10]; a[11]=s5[1]+cl[9*D+c+11];
    a[12]=s6[0]+cl[9*D+c+12]; a[13]=s6[1]+cl[9*D+c+13];
    a[14]=s7[0]+cl[9*D+c+14]; a[15]=s7[1]+cl[9*D+c+15];
  }
  int beg = rowptr[nd], end = rowptr[nd+1];
  unsigned long long cp = 0;             // 9 codes x 7-bit counters
  unsigned p[16], pn[16];
  {
    int m0 = end - beg;
    #pragma unroll
    for (int k = 0; k < 16; ++k) if (k < m0) p[k] = packed[beg+k];
  }
  for (int j = beg; j < end; j += 16){
    int m = end - j;                     // uniform within 8-lane group
    uint4 v[16];
    #pragma unroll
    for (int k = 0; k < 16; ++k) if (k < m)
      v[k] = *(const uint4*)(h + (size_t)(p[k] & 0xFFFFFu)*D + c);
    int mn = end - (j + 16);             // prefetch next batch's indices
    #pragma unroll
    for (int k = 0; k < 16; ++k) if (k < mn) pn[k] = packed[j+16+k];
    #pragma unroll
    for (int k = 0; k < 16; ++k) if (k < m){
      cp += 1ULL << (7*(int)(p[k] >> 20));
      floatx2 g0 = __builtin_amdgcn_cvt_pk_f32_fp8((int)v[k].x, false);
      floatx2 g1 = __builtin_amdgcn_cvt_pk_f32_fp8((int)v[k].x, true);
      floatx2 g2 = __builtin_amdgcn_cvt_pk_f32_fp8((int)v[k].y, false);
      floatx2 g3 = __builtin_amdgcn_cvt_pk_f32_fp8((int)v[k].y, true);
      floatx2 g4 = __builtin_amdgcn_cvt_pk_f32_fp8((int)v[k].z, false);
      floatx2 g5 = __builtin_amdgcn_cvt_pk_f32_fp8((int)v[k].z, true);
      floatx2 g6 = __builtin_amdgcn_cvt_pk_f32_fp8((int)v[k].w, false);
      floatx2 g7 = __builtin_amdgcn_cvt_pk_f32_fp8((int)v[k].w, true);
      a[0]+=g0[0];  a[1]+=g0[1];  a[2]+=g1[0];  a[3]+=g1[1];
      a[4]+=g2[0];  a[5]+=g2[1];  a[6]+=g3[0];  a[7]+=g3[1];
      a[8]+=g4[0];  a[9]+=g4[1];  a[10]+=g5[0]; a[11]+=g5[1];
      a[12]+=g6[0]; a[13]+=g6[1]; a[14]+=g7[0]; a[15]+=g7[1];
    }
    #pragma unroll
    for (int k = 0; k < 16; ++k) p[k] = pn[k];
  }
  #pragma unroll
  for (int cd = 0; cd < 9; ++cd){
    float cnt = (float)(int)((cp >> (7*cd)) & 127);
    #pragma unroll
    for (int d0 = 0; d0 < 16; ++d0)
      a[d0] += cnt * cl[cd*D + c + d0];
  }
  if (valid){
    half8 o0, o1;
    #pragma unroll
    for (int j = 0; j < 8; ++j){ o0[j] = (_Float16)a[j]; o1[j] = (_Float16)a[8+j]; }
    *(half8*)(agg + (size_t)node*D + c)     = o0;
    *(half8*)(agg + (size_t)node*D + c + 8) = o1;
  }
}

// ---------------- fused GIN MLP (R6 verified shape): A->LDS(swizzled), GEMM1+ReLU -> GEMM2+BN
// LDS staging is load-bearing (r12: direct global A loads regressed 41->54us). DO NOT remove.
__global__ __launch_bounds__(256) void mlp_kernel(
    const _Float16* __restrict__ agg, const _Float16* __restrict__ w1f,
    const _Float16* __restrict__ w2f, const float* __restrict__ b1,
    const float* __restrict__ sc, const float* __restrict__ sh,
    unsigned char* __restrict__ hout, float* __restrict__ fout,
    int N, int relu_out){
  __shared__ __align__(16) char smem[64*256*2];
  _Float16* atile = (_Float16*)smem;   // row*128 + (c8 ^ (row&15))*8 + (col&7)
  _Float16* hmid  = (_Float16*)smem;   // row*256 + (c8 ^ (row&31))*8 + (col&7)
  int tid = threadIdx.x;
  int wave = tid >> 6, lane = tid & 63;
  int quad = lane >> 4, l15 = lane & 15;
  int r0 = blockIdx.x * 64;

  half8 zf;
  #pragma unroll
  for (int j = 0; j < 8; ++j) zf[j] = (_Float16)0.f;

  #pragma unroll
  for (int i = 0; i < 4; ++i){
    int ci = i*256 + tid;
    int row = ci >> 4, c8 = ci & 15;
    int m = r0 + row;
    half8 v = (m < N) ? *(const half8*)(agg + (size_t)m*D + c8*8) : zf;
    *(half8*)(atile + row*128 + ((c8 ^ (row & 15)) * 8)) = v;
  }
  __syncthreads();

  floatx4 acc[4][4] = {};
  half8 bcur[4], bnxt[4];
  #pragma unroll
  for (int nt = 0; nt < 4; ++nt)
    bcur[nt] = *(const half8*)(w1f + (size_t)quad*(H*8) + (wave*64 + nt*16 + l15)*8);
  #pragma unroll
  for (int ks = 0; ks < 4; ++ks){
    if (ks < 3){
      #pragma unroll
      for (int nt = 0; nt < 4; ++nt)
        bnxt[nt] = *(const half8*)(w1f + (size_t)((ks+1)*4 + quad)*(H*8) + (wave*64 + nt*16 + l15)*8);
    }
    int c8 = ks*4 + quad;
    half8 af[4];
    #pragma unroll
    for (int mt = 0; mt < 4; ++mt)
      af[mt] = *(const half8*)(atile + (mt*16 + l15)*128 + ((c8 ^ l15) * 8));
    #pragma unroll
    for (int mt = 0; mt < 4; ++mt)
      #pragma unroll
      for (int nt = 0; nt < 4; ++nt)
        acc[mt][nt] = __builtin_amdgcn_mfma_f32_16x16x32_f16(af[mt], bcur[nt], acc[mt][nt], 0, 0, 0);
    #pragma unroll
    for (int nt = 0; nt < 4; ++nt) bcur[nt] = bnxt[nt];
  }
  __syncthreads();

  #pragma unroll
  for (int nt = 0; nt < 4; ++nt){
    int n = wave*64 + nt*16 + l15;
    float bias = b1[n];
    #pragma unroll
    for (int mt = 0; mt < 4; ++mt)
      #pragma unroll
      for (int r = 0; r < 4; ++r){
        int row = mt*16 + quad*4 + r;
        hmid[row*256 + (((n >> 3) ^ (row & 31)) * 8) + (n & 7)] =
            (_Float16)fmaxf(acc[mt][nt][r] + bias, 0.f);
      }
  }
  __syncthreads();

  floatx4 acc2[4][2] = {};
  half8 gcur[2], gnxt[2];
  #pragma unroll
  for (int nt = 0; nt < 2; ++nt)
    gcur[nt] = *(const half8*)(w2f + (size_t)quad*(D*8) + (wave*32 + nt*16 + l15)*8);
  #pragma unroll
  for (int ks = 0; ks < 8; ++ks){
    if (ks < 7){
      #pragma unroll
      for (int nt = 0; nt < 2; ++nt)
        gnxt[nt] = *(const half8*)(w2f + (size_t)((ks+1)*4 + quad)*(D*8) + (wave*32 + nt*16 + l15)*8);
    }
    int c8 = ks*4 + quad;
    half8 af[4];
    #pragma unroll
    for (int mt = 0; mt < 4; ++mt){
      int row = mt*16 + l15;
      af[mt] = *(const half8*)(hmid + row*256 + ((c8 ^ (row & 31)) * 8));
    }
    #pragma unroll
    for (int mt = 0; mt < 4; ++mt)
      #pragma unroll
      for (int nt = 0; nt < 2; ++nt)
        acc2[mt][nt] = __builtin_amdgcn_mfma_f32_16x16x32_f16(af[mt], gcur[nt], acc2[mt][nt], 0, 0, 0);
    #pragma unroll
    for (int nt = 0; nt < 2; ++nt) gcur[nt] = gnxt[nt];
  }

  #pragma unroll
  for (int nt = 0; nt < 2; ++nt){
    int n = wave*32 + nt*16 + l15;
    float A = sc[n], B = sh[n];
    #pragma unroll
    for (int mt = 0; mt < 4; ++mt)
      #pragma unroll
      for (int r = 0; r < 4; ++r){
        int row = r0 + mt*16 + quad*4 + r;
        if (row < N){
          float v = acc2[mt][nt][r]*A + B;
          if (relu_out) v = fmaxf(v, 0.f);
          if (fout) fout[(size_t)row*D + n] = v;
          else      hout[(size_t)row*D + n] = f32_to_fp8(v);
        }
      }
  }
}

extern "C" void kernel_launch(void* const* d_in, const int* in_sizes, int n_in,
                              void* d_out, int out_size, void* d_ws, size_t ws_size,
                              hipStream_t stream){
  const int*   x     = (const int*)d_in[0];
  const int*   ei    = (const int*)d_in[1];
  const int*   ea    = (const int*)d_in[2];
  const float* xemb  = (const float*)d_in[3];
  const float* etab  = (const float*)d_in[4];
  const float* w1    = (const float*)d_in[5];
  const float* b1    = (const float*)d_in[6];
  const float* w2    = (const float*)d_in[7];
  const float* b2    = (const float*)d_in[8];
  const float* gamma = (const float*)d_in[9];
  const float* beta  = (const float*)d_in[10];
  const float* mean  = (const float*)d_in[11];
  const float* var   = (const float*)d_in[12];
  float* out = (float*)d_out;

  int N = in_sizes[0] / 2;
  int E = in_sizes[1] / 2;
  int nbuck = (N + 255) >> 8;
  int M = nbuck * NBLK;
  int nbM = (M + 1023) / 1024;
  int chunk = (E + NBLK - 1) / NBLK;

  char* ws = (char*)d_ws;
  size_t off = 0;
  auto alloc = [&](size_t b){ void* p = ws + off; off += (b + 255) & ~(size_t)255; return p; };
  unsigned char* h   = (unsigned char*)alloc((size_t)N*D);      // fp8 node table
  _Float16* agg      = (_Float16*)alloc((size_t)N*D*2);         // staged aliases this
  unsigned* packed   = (unsigned*)alloc((size_t)(E+64)*4);
  int*      rowptr   = (int*)alloc((size_t)(N+1)*4);
  int*      cntBB    = (int*)alloc((size_t)M*4);
  int*      baseBB   = (int*)alloc((size_t)(M+1)*4);
  int*      bsum     = (int*)alloc((size_t)nbM*4);
  int*      bbase    = (int*)alloc((size_t)nbM*4);
  _Float16* w1f      = (_Float16*)alloc((size_t)5*H*D*2);
  _Float16* w2f      = (_Float16*)alloc((size_t)5*D*H*2);
  float*    comb     = (float*)alloc((size_t)5*10*D*4);
  float*    sc       = (float*)alloc((size_t)5*D*4);
  float*    sh       = (float*)alloc((size_t)5*D*4);
  unsigned* staged   = (unsigned*)agg;   // dead before agg_kernel first writes agg

  const int* srcp = ei;
  const int* dstp = ei + E;

  part_count<<<NBLK, 256, 0, stream>>>(dstp, cntBB, E, chunk, nbuck);
  scan_part <<<nbM, 256, 0, stream>>>(cntBB, bsum, M);
  scan_bsums<<<1, 1024, 0, stream>>>(bsum, bbase, baseBB, nbM, M);   // baseBB[M] = E
  scan_emit <<<nbM, 256, 0, stream>>>(cntBB, bbase, baseBB, M);
  part_bin  <<<NBLK, 256, 0, stream>>>(srcp, dstp, ea, baseBB, staged, E, chunk, nbuck);
  part_emit <<<nbuck, 256, 0, stream>>>(staged, baseBB, packed, rowptr, N, E, nbuck, M);
  repack_weights<<<(5*H*D+255)/256, 256, 0, stream>>>(w1, w2, w1f, w2f, 5*H*D);
  prep_tables<<<5, 128, 0, stream>>>(etab, gamma, beta, mean, var, b2, comb, sc, sh);
  embed_kernel<<<((size_t)N*16+255)/256, 256, 0, stream>>>(x, xemb, h, N);

  for (int l = 0; l < 5; ++l){
    agg_kernel<<<(N+31)/32, 256, 0, stream>>>(h, packed, rowptr, comb + (size_t)l*10*D, agg, N);
    int last = (l == 4);
    mlp_kernel<<<(N+63)/64, 256, 0, stream>>>(agg, w1f + (size_t)l*H*D, w2f + (size_t)l*D*H,
        b1 + (size_t)l*H, sc + (size_t)l*D, sh + (size_t)l*D,
        last ? (unsigned char*)nullptr : h, last ? out : (float*)nullptr,
        N, last ? 0 : 1);
  }
}